// Round 1
// baseline (418.903 us; speedup 1.0000x reference)
//
#include <hip/hip_runtime.h>

#define F 256
#define TWO_F 512

// ---------- bf16 helpers (manual, RNE) ----------
static __device__ __forceinline__ unsigned short f2bf(float f) {
    unsigned u = __float_as_uint(f);
    u += 0x7FFFu + ((u >> 16) & 1u);
    return (unsigned short)(u >> 16);
}
static __device__ __forceinline__ float bf2f(unsigned short u) {
    return __uint_as_float(((unsigned)u) << 16);
}

// ---------- kernel 1: repack W1 into k-major Wc_t[k][j], j<256 -> W1a, j>=256 -> W1b ----------
__global__ void prep_w_kernel(const float* __restrict__ W1, float* __restrict__ wt) {
    int i = blockIdx.x * blockDim.x + threadIdx.x;
    if (i >= F * TWO_F) return;
    int k = i >> 9;       // 0..255
    int j = i & 511;      // 0..511
    wt[i] = (j < F) ? W1[j * TWO_F + k] : W1[(j - F) * TWO_F + F + k];
}

// ---------- kernel 2: C[n][j] = sum_k h[n][k] * wt[k][j], stored bf16 ----------
#define TM 128
#define TN 64
#define TK 32
#define HT_STRIDE 132   // padded so transpose-store conflicts stay mild; keeps 16B alignment

__global__ __launch_bounds__(256) void gemm_kernel(
    const float* __restrict__ h, const float* __restrict__ wt,
    unsigned short* __restrict__ C, int M)
{
    __shared__ float hT[TK][HT_STRIDE];  // [k][m] transposed A tile
    __shared__ float wT[TK][TN];         // [k][j]

    const int tid = threadIdx.x;
    const int bm = blockIdx.x * TM;
    const int bn = blockIdx.y * TN;
    const int tx = tid & 15;    // col group: cols tx*4 .. tx*4+3
    const int ty = tid >> 4;    // row group: rows ty*8 .. ty*8+7
    const int lrow = tid >> 3;        // h-load: 8 threads per row
    const int lkv  = (tid & 7) << 2;  // h-load: k offset (float4)
    const int wrow = tid >> 4;        // w-load: 16 float4 per row
    const int wcol = (tid & 15) << 2;

    float acc[8][4];
    #pragma unroll
    for (int i = 0; i < 8; ++i)
        #pragma unroll
        for (int j = 0; j < 4; ++j) acc[i][j] = 0.f;

    for (int k0 = 0; k0 < F; k0 += TK) {
        // stage h tile (transposed into LDS)
        #pragma unroll
        for (int p = 0; p < 4; ++p) {
            int m = lrow + p * 32;
            int gm = bm + m;
            float4 v = make_float4(0.f, 0.f, 0.f, 0.f);
            if (gm < M) v = *(const float4*)(h + (size_t)gm * F + k0 + lkv);
            hT[lkv + 0][m] = v.x;
            hT[lkv + 1][m] = v.y;
            hT[lkv + 2][m] = v.z;
            hT[lkv + 3][m] = v.w;
        }
        // stage w tile (already k-major, straight copy)
        #pragma unroll
        for (int p = 0; p < 2; ++p) {
            int kk = wrow + p * 16;
            float4 v = *(const float4*)(wt + (size_t)(k0 + kk) * TWO_F + bn + wcol);
            *(float4*)&wT[kk][wcol] = v;
        }
        __syncthreads();

        #pragma unroll
        for (int k = 0; k < TK; ++k) {
            float4 a0 = *(const float4*)&hT[k][ty * 8];
            float4 a1 = *(const float4*)&hT[k][ty * 8 + 4];
            float4 b  = *(const float4*)&wT[k][tx * 4];
            float av[8] = {a0.x, a0.y, a0.z, a0.w, a1.x, a1.y, a1.z, a1.w};
            float bv[4] = {b.x, b.y, b.z, b.w};
            #pragma unroll
            for (int i = 0; i < 8; ++i)
                #pragma unroll
                for (int j = 0; j < 4; ++j)
                    acc[i][j] = fmaf(av[i], bv[j], acc[i][j]);
        }
        __syncthreads();
    }

    #pragma unroll
    for (int i = 0; i < 8; ++i) {
        int gm = bm + ty * 8 + i;
        if (gm < M) {
            ushort4 o;
            o.x = f2bf(acc[i][0]);
            o.y = f2bf(acc[i][1]);
            o.z = f2bf(acc[i][2]);
            o.w = f2bf(acc[i][3]);
            *(ushort4*)(C + (size_t)gm * TWO_F + bn + tx * 4) = o;
        }
    }
}

// ---------- kernel 3: per-edge score, one edge per wave ----------
__global__ __launch_bounds__(256) void edge_kernel(
    const unsigned short* __restrict__ C,
    const int* __restrict__ src, const int* __restrict__ dst,
    const float* __restrict__ w2, const float* __restrict__ b1v,
    const float* __restrict__ b2, float* __restrict__ out, int E)
{
    const int lane = threadIdx.x & 63;
    const int e = blockIdx.x * 4 + (threadIdx.x >> 6);
    if (e >= E) return;
    const int s = src[e];
    const int d = dst[e];
    ushort4 av = *(const ushort4*)(C + (size_t)s * TWO_F + lane * 4);
    ushort4 bv = *(const ushort4*)(C + (size_t)d * TWO_F + F + lane * 4);
    float4 w  = *(const float4*)(w2 + lane * 4);
    float4 bb = *(const float4*)(b1v + lane * 4);

    float sum;
    sum  = w.x * fmaxf(bf2f(av.x) + bf2f(bv.x) + bb.x, 0.f);
    sum += w.y * fmaxf(bf2f(av.y) + bf2f(bv.y) + bb.y, 0.f);
    sum += w.z * fmaxf(bf2f(av.z) + bf2f(bv.z) + bb.z, 0.f);
    sum += w.w * fmaxf(bf2f(av.w) + bf2f(bv.w) + bb.w, 0.f);

    #pragma unroll
    for (int off = 32; off > 0; off >>= 1)
        sum += __shfl_down(sum, off);

    if (lane == 0) out[e] = sum + b2[0];
}

extern "C" void kernel_launch(void* const* d_in, const int* in_sizes, int n_in,
                              void* d_out, int out_size, void* d_ws, size_t ws_size,
                              hipStream_t stream) {
    const float* h    = (const float*)d_in[0];
    const int*   src  = (const int*)d_in[1];
    const int*   dst  = (const int*)d_in[2];
    const float* W1_w = (const float*)d_in[3];
    const float* W1_b = (const float*)d_in[4];
    const float* W2_w = (const float*)d_in[5];
    const float* W2_b = (const float*)d_in[6];
    float* out = (float*)d_out;

    const int M = in_sizes[0] / F;   // 50000 nodes
    const int E = in_sizes[1];       // 800000 edges

    // workspace layout: [Wc_t fp32: 256*512*4 = 512KB][C bf16: M*512*2 ~= 51.2MB]
    float* wt = (float*)d_ws;
    unsigned short* C = (unsigned short*)((char*)d_ws + (size_t)F * TWO_F * sizeof(float));

    prep_w_kernel<<<(F * TWO_F + 255) / 256, 256, 0, stream>>>(W1_w, wt);

    dim3 ggrid((M + TM - 1) / TM, TWO_F / TN);
    gemm_kernel<<<ggrid, 256, 0, stream>>>(h, wt, C, M);

    edge_kernel<<<(E + 3) / 4, 256, 0, stream>>>(C, src, dst, W2_w, W1_b, W2_b, out, E);
}

// Round 2
// 244.453 us; speedup vs baseline: 1.7136x; 1.7136x over previous
//
#include <hip/hip_runtime.h>

#define F 256
#define TWO_F 512
#define BM 128
#define BN 128
#define BK 64

typedef __attribute__((ext_vector_type(8))) short short8;
typedef __attribute__((ext_vector_type(4))) float float4v;

// ---------- bf16 helpers (manual, RNE) ----------
static __device__ __forceinline__ unsigned short f2bf(float f) {
    unsigned u = __float_as_uint(f);
    u += 0x7FFFu + ((u >> 16) & 1u);
    return (unsigned short)(u >> 16);
}
static __device__ __forceinline__ float blo(unsigned u) { return __uint_as_float(u << 16); }
static __device__ __forceinline__ float bhi(unsigned u) { return __uint_as_float(u & 0xFFFF0000u); }

// ---------- kernel 1: W1 fp32 [256][512] -> Wb bf16 [n][k], n in 0..511 ----------
// n < 256: Wb[n][k] = W1[n][k]        (src-half weights)
// n >= 256: Wb[n][k] = W1[n-256][256+k] (dst-half weights)
__global__ void prep_w_kernel(const float* __restrict__ W1, unsigned short* __restrict__ Wb) {
    int i = blockIdx.x * blockDim.x + threadIdx.x;
    if (i >= TWO_F * F) return;
    int n = i >> 8;
    int k = i & 255;
    float v = W1[(n & 255) * TWO_F + ((n >> 8) << 8) + k];
    Wb[i] = f2bf(v);
}

// ---------- kernel 2: C[m][n] = sum_k h[m][k] * Wb[n][k], bf16 MFMA, C stored bf16 ----------
__global__ __launch_bounds__(256) void gemm_kernel(
    const float* __restrict__ h, const unsigned short* __restrict__ Wb,
    unsigned short* __restrict__ C, int M)
{
    __shared__ unsigned short sA[BM * BK];  // [m][k], row stride 64 bf16 = 128 B
    __shared__ unsigned short sB[BN * BK];  // [n][k], row stride 64 bf16 = 128 B

    const int tid  = threadIdx.x;
    const int lane = tid & 63;
    const int wid  = tid >> 6;          // 4 waves
    const int wm   = wid >> 1;          // 0..1
    const int wn   = wid & 1;           // 0..1
    const int bm   = blockIdx.x * BM;
    const int bn   = blockIdx.y * BN;

    // A staging: thread t -> row ar = t>>1 (0..127), k-segment ak = (t&1)*32
    const int ar = tid >> 1;
    const int ak = (tid & 1) * 32;
    const bool a_ok = (bm + ar) < M;
    const float* hrow = h + (size_t)(bm + ar) * F + ak;

    // B staging via global_load_lds: wave covers rows wid*32 .. wid*32+31, 4 issues of 8 rows
    const int brow0 = wid * 32;
    const int b_r   = lane >> 3;        // row within 8-row issue
    const int b_k   = (lane & 7) * 8;   // k offset (elements) for 16B chunk

    float4v acc[4][4];
    #pragma unroll
    for (int i = 0; i < 4; ++i)
        #pragma unroll
        for (int j = 0; j < 4; ++j)
            acc[i][j] = (float4v)(0.f);

    const int quad = lane >> 4;
    const int l15  = lane & 15;

    for (int k0 = 0; k0 < F; k0 += BK) {
        // --- B tile: async global -> LDS, 16B per lane ---
        #pragma unroll
        for (int p = 0; p < 4; ++p) {
            int r = brow0 + p * 8;
            const unsigned short* gp = Wb + (size_t)(bn + r + b_r) * F + k0 + b_k;
            __builtin_amdgcn_global_load_lds(
                (const __attribute__((address_space(1))) unsigned int*)gp,
                (__attribute__((address_space(3))) unsigned int*)&sB[r * BK],
                16, 0, 0);
        }

        // --- A tile: fp32 global -> cvt bf16 -> LDS ---
        float4 av[8];
        if (a_ok) {
            const float* p = hrow + k0;
            #pragma unroll
            for (int i = 0; i < 8; ++i) av[i] = *(const float4*)(p + i * 4);
        } else {
            #pragma unroll
            for (int i = 0; i < 8; ++i) av[i] = make_float4(0.f, 0.f, 0.f, 0.f);
        }
        #pragma unroll
        for (int i2 = 0; i2 < 4; ++i2) {
            union { unsigned short us[8]; uint4 v; } pk;
            pk.us[0] = f2bf(av[2 * i2].x);
            pk.us[1] = f2bf(av[2 * i2].y);
            pk.us[2] = f2bf(av[2 * i2].z);
            pk.us[3] = f2bf(av[2 * i2].w);
            pk.us[4] = f2bf(av[2 * i2 + 1].x);
            pk.us[5] = f2bf(av[2 * i2 + 1].y);
            pk.us[6] = f2bf(av[2 * i2 + 1].z);
            pk.us[7] = f2bf(av[2 * i2 + 1].w);
            *(uint4*)&sA[ar * BK + ak + i2 * 8] = pk.v;
        }
        __syncthreads();

        // --- MFMA: 2 k-steps of 32 ---
        #pragma unroll
        for (int ks = 0; ks < 2; ++ks) {
            short8 afr[4], bfr[4];
            #pragma unroll
            for (int mt = 0; mt < 4; ++mt)
                afr[mt] = *(const short8*)&sA[(wm * 64 + mt * 16 + l15) * BK + ks * 32 + quad * 8];
            #pragma unroll
            for (int nt = 0; nt < 4; ++nt)
                bfr[nt] = *(const short8*)&sB[(wn * 64 + nt * 16 + l15) * BK + ks * 32 + quad * 8];
            #pragma unroll
            for (int mt = 0; mt < 4; ++mt)
                #pragma unroll
                for (int nt = 0; nt < 4; ++nt)
                    acc[mt][nt] = __builtin_amdgcn_mfma_f32_16x16x32_bf16(
                        afr[mt], bfr[nt], acc[mt][nt], 0, 0, 0);
        }
        __syncthreads();
    }

    // --- epilogue: C/D layout col=lane&15, row=(lane>>4)*4+reg ---
    #pragma unroll
    for (int mt = 0; mt < 4; ++mt) {
        int gm0 = bm + wm * 64 + mt * 16 + quad * 4;
        #pragma unroll
        for (int r = 0; r < 4; ++r) {
            int gm = gm0 + r;
            if (gm < M) {
                unsigned short* cp = C + (size_t)gm * TWO_F + bn + wn * 64 + l15;
                #pragma unroll
                for (int nt = 0; nt < 4; ++nt)
                    cp[nt * 16] = f2bf(acc[mt][nt][r]);
            }
        }
    }
}

// ---------- kernel 3: per-edge score, one edge per 32 lanes, 16B loads ----------
__global__ __launch_bounds__(256) void edge_kernel(
    const unsigned short* __restrict__ C,
    const int* __restrict__ src, const int* __restrict__ dst,
    const float* __restrict__ w2, const float* __restrict__ b1v,
    const float* __restrict__ b2, float* __restrict__ out, int E)
{
    const int lane = threadIdx.x & 31;
    const int e = blockIdx.x * 8 + (threadIdx.x >> 5);
    if (e >= E) return;
    const int s = src[e];
    const int d = dst[e];

    uint4 av = *(const uint4*)(C + (size_t)s * TWO_F + lane * 8);        // A-half elems lane*8..+7
    uint4 bv = *(const uint4*)(C + (size_t)d * TWO_F + F + lane * 8);    // B-half
    float4 w0 = *(const float4*)(w2 + lane * 8);
    float4 w1 = *(const float4*)(w2 + lane * 8 + 4);
    float4 c0 = *(const float4*)(b1v + lane * 8);
    float4 c1 = *(const float4*)(b1v + lane * 8 + 4);

    float sum;
    sum  = w0.x * fmaxf(blo(av.x) + blo(bv.x) + c0.x, 0.f);
    sum += w0.y * fmaxf(bhi(av.x) + bhi(bv.x) + c0.y, 0.f);
    sum += w0.z * fmaxf(blo(av.y) + blo(bv.y) + c0.z, 0.f);
    sum += w0.w * fmaxf(bhi(av.y) + bhi(bv.y) + c0.w, 0.f);
    sum += w1.x * fmaxf(blo(av.z) + blo(bv.z) + c1.x, 0.f);
    sum += w1.y * fmaxf(bhi(av.z) + bhi(bv.z) + c1.y, 0.f);
    sum += w1.z * fmaxf(blo(av.w) + blo(bv.w) + c1.z, 0.f);
    sum += w1.w * fmaxf(bhi(av.w) + bhi(bv.w) + c1.w, 0.f);

    #pragma unroll
    for (int off = 16; off > 0; off >>= 1)
        sum += __shfl_down(sum, off, 32);

    if (lane == 0) out[e] = sum + b2[0];
}

extern "C" void kernel_launch(void* const* d_in, const int* in_sizes, int n_in,
                              void* d_out, int out_size, void* d_ws, size_t ws_size,
                              hipStream_t stream) {
    const float* h    = (const float*)d_in[0];
    const int*   src  = (const int*)d_in[1];
    const int*   dst  = (const int*)d_in[2];
    const float* W1_w = (const float*)d_in[3];
    const float* W1_b = (const float*)d_in[4];
    const float* W2_w = (const float*)d_in[5];
    const float* W2_b = (const float*)d_in[6];
    float* out = (float*)d_out;

    const int M = in_sizes[0] / F;   // 50000 nodes
    const int E = in_sizes[1];       // 800000 edges

    // ws layout: [Wb bf16: 512*256*2 = 256KB][pad to 512KB][C bf16: M*512*2 ~= 51.2MB]
    unsigned short* Wb = (unsigned short*)d_ws;
    unsigned short* C  = (unsigned short*)((char*)d_ws + 512 * 1024);

    prep_w_kernel<<<(TWO_F * F + 255) / 256, 256, 0, stream>>>(W1_w, Wb);

    dim3 ggrid((M + BM - 1) / BM, TWO_F / BN);
    gemm_kernel<<<ggrid, 256, 0, stream>>>(h, Wb, C, M);

    edge_kernel<<<(E + 7) / 8, 256, 0, stream>>>(C, src, dst, W2_w, W1_b, W2_b, out, E);
}